// Round 9
// baseline (375.375 us; speedup 1.0000x reference)
//
#include <hip/hip_runtime.h>

#define H 256
#define W 256
#define BATCH 8
#define CIN 16
#define TW 32
#define TH 4
#define HWC (TW + 2)        // 34 halo cols
#define HHC (TH + 2)        // 6 halo rows
#define NHALO (HWC * HHC)   // 204 halo pixels
#define PXA 40              // bytes per halo pixel (32 data + 8 pad) -> spread banks
#define FIX_CAP 16384
#define GAP_TAU 6e-3f

// LDS layout (bytes): bufB dbuf 16384 | xH 204*40=8160 | gs 816 | bias 256 = 25616
#define OFF_XH   16384
#define OFF_GS   24544
#define OFF_BIAS 25360
#define SMEM_BYTES 25616

typedef __attribute__((ext_vector_type(8))) short short8;       // 8 fp16 bit-patterns
typedef __attribute__((ext_vector_type(8))) _Float16 half8;     // MFMA A/B frag
typedef __attribute__((ext_vector_type(4))) float f32x4;        // MFMA C/D frag

union S8H8 { short8 s; half8 h; };
__device__ __forceinline__ half8 as_h8(short8 s) { S8H8 u; u.s = s; return u.h; }
union HU { _Float16 h; unsigned short u; };
__device__ __forceinline__ unsigned short f2h(float f) { HU u; u.h = (_Float16)f; return u.u; }

__device__ __forceinline__ void gload_lds16(const void* g, void* l) {
    __builtin_amdgcn_global_load_lds(
        (const __attribute__((address_space(1))) unsigned int*)g,
        (__attribute__((address_space(3))) unsigned int*)l, 16, 0, 0);
}

// VALU-only cross-lane max within each 16-lane row (no DS pipe traffic); HW-verified R8.
template <int CTRL>
__device__ __forceinline__ float dpp_maxstep(float v) {
    int t = __builtin_amdgcn_update_dpp(0, __float_as_int(v), CTRL, 0xF, 0xF, true);
    return fmaxf(v, __int_as_float(t));
}
__device__ __forceinline__ float rowmax16(float v) {
    v = dpp_maxstep<0xB1>(v);     // quad_perm xor1
    v = dpp_maxstep<0x4E>(v);     // quad_perm xor2
    v = dpp_maxstep<0x124>(v);    // row_ror:4
    v = dpp_maxstep<0x128>(v);    // row_ror:8
    return v;
}

// weight [oc=n][ic=k][3][3] fp32 -> fp16 (x64), fragment-major:
//   short addr = ((tap*2+ks)*4 + nt)*512 + (q*16 + lm)*8 + j
//   where n = nt*16+lm, k = ks*32 + q*8 + j  (R1-verified k = q*8+j mapping)
// Also zeroes fix_cnt.
__global__ void wprep_kernel(const float* __restrict__ w, unsigned short* __restrict__ wt,
                             unsigned* __restrict__ fix_cnt) {
    const int n = blockIdx.x;        // 64 blocks
    const int k = threadIdx.x;       // 64 threads
    if (n == 0 && k == 0) fix_cnt[0] = 0u;

    const int nt = n >> 4, lm = n & 15;
    const int ks = k >> 5, q = (k >> 3) & 3, j = k & 7;
    const int dst = ((0 * 2 + ks) * 4 + nt) * 512 + (q * 16 + lm) * 8 + j;
#pragma unroll
    for (int t = 0; t < 9; ++t)
        wt[dst + t * 4096] = f2h(w[(n * 64 + k) * 9 + t] * 64.0f);
}

__global__ __launch_bounds__(256, 4) void ssconv_f16_kernel(
    const float* __restrict__ x, const int* __restrict__ gidx,
    const unsigned short* __restrict__ wt, const float* __restrict__ bias,
    float* __restrict__ out_sel, float* __restrict__ out_idx,
    unsigned* __restrict__ fix_cnt, unsigned* __restrict__ fix_list)
{
    __shared__ __align__(16) char smem[SMEM_BYTES];
    char*  bufB  = smem;                       // 2 x 8192, double buffer
    char*  xH    = smem + OFF_XH;              // fp16 halo, PXA-stride
    int*   gsL   = (int*)(smem + OFF_GS);
    float* biasL = (float*)(smem + OFF_BIAS);

    const int tid  = threadIdx.x;
    const int x0   = blockIdx.x * TW;
    const int y0   = blockIdx.y * TH;
    const int bz   = blockIdx.z;
    const int wvid = tid >> 6;            // wave 0..3 -> tile row
    const int L    = tid & 63;
    const int q    = L >> 4;
    const int lm   = L & 15;
    const int c0   = (q & 1) * 8;         // channel half within pixel

    // ---- issue B(tap=0) -> buf0 (8192 B: 2 x 4KB block-wide issues) ----
#pragma unroll
    for (int it = 0; it < 2; ++it) {
        int seg = it * 4 + wvid;          // 8 segments of 1KB, wave-uniform base
        gload_lds16((const char*)wt + seg * 1024 + L * 16, bufB + seg * 1024 + L * 16);
    }

    if (tid < 64) biasL[tid] = bias[tid];

    // ---- stage halo as fp16 (no scale needed) + group map ----
    if (tid < NHALO) {
        int r = tid / HWC, c = tid - r * HWC;
        int hy = y0 + r - 1, hx = x0 + c - 1;
        float4 a0 = make_float4(0, 0, 0, 0), a1 = a0, a2 = a0, a3 = a0;
        int g = 0;
        if (hy >= 0 && hy < H && hx >= 0 && hx < W) {
            const float4* src = (const float4*)(x + (((size_t)bz * H + hy) * W + hx) * CIN);
            a0 = src[0]; a1 = src[1]; a2 = src[2]; a3 = src[3];
            g = gidx[((size_t)bz * H + hy) * W + hx];
        }
        short8 v0, v1;
        v0[0] = (short)f2h(a0.x); v0[1] = (short)f2h(a0.y); v0[2] = (short)f2h(a0.z); v0[3] = (short)f2h(a0.w);
        v0[4] = (short)f2h(a1.x); v0[5] = (short)f2h(a1.y); v0[6] = (short)f2h(a1.z); v0[7] = (short)f2h(a1.w);
        v1[0] = (short)f2h(a2.x); v1[1] = (short)f2h(a2.y); v1[2] = (short)f2h(a2.z); v1[3] = (short)f2h(a2.w);
        v1[4] = (short)f2h(a3.x); v1[5] = (short)f2h(a3.y); v1[6] = (short)f2h(a3.z); v1[7] = (short)f2h(a3.w);
        *(short8*)(xH + tid * PXA + 0)  = v0;
        *(short8*)(xH + tid * PXA + 16) = v1;
        gsL[tid] = g;
    }
    __syncthreads();   // halo ready; drains B(0) prefetch vmcnt

    f32x4 acc[2][4] = {};   // [m][nt], fp32

    // ---- main loop: per-tap B double-buffer, fragment-major conflict-free reads ----
#pragma unroll 1
    for (int tap = 0; tap < 9; ++tap) {
        if (tap < 8) {   // prefetch next tap's B into the other half
            const char* gsrc = (const char*)wt + (size_t)(tap + 1) * 8192;
            char* ldst = bufB + ((tap + 1) & 1) * 8192;
#pragma unroll
            for (int it = 0; it < 2; ++it) {
                int seg = it * 4 + wvid;
                gload_lds16(gsrc + seg * 1024 + L * 16, ldst + seg * 1024 + L * 16);
            }
        }

        const char* bB = bufB + (tap & 1) * 8192;
        const int dy = tap / 3, dx = tap - dy * 3;
        const int hbase = (wvid + dy) * HWC + lm + dx;

        // A fragments + groups, loaded once per tap
        int gg[2];
        short8 ah[2];
#pragma unroll
        for (int m = 0; m < 2; ++m) {
            int hb = hbase + 16 * m;
            gg[m] = gsL[hb];
            ah[m] = *(const short8*)(xH + hb * PXA + c0 * 2);
        }

        const short8 z = (short8)0;
#pragma unroll
        for (int ks = 0; ks < 2; ++ks) {
            const int gk = ks * 2 + (q >> 1);
            short8 bh[4];
#pragma unroll
            for (int nt = 0; nt < 4; ++nt)
                bh[nt] = *(const short8*)(bB + (ks * 4 + nt) * 1024 + L * 16);
#pragma unroll
            for (int m = 0; m < 2; ++m) {
                short8 a0 = (gg[m] == gk) ? ah[m] : z;
#pragma unroll
                for (int nt = 0; nt < 4; ++nt)
                    acc[m][nt] = __builtin_amdgcn_mfma_f32_16x16x32_f16(
                        as_h8(a0), as_h8(bh[nt]), acc[m][nt], 0, 0, 0);
            }
        }
        __syncthreads();   // done reading bB; prefetch landed
    }

    // ---- epilogue: all-register. channel = lm (out-group = nt), pixel col = m*16+q*4+r.
    //      DPP row-of-16 maxout, no DS. out = acc/64 + bias. ----
    float bsr[4];
#pragma unroll
    for (int nt = 0; nt < 4; ++nt) bsr[nt] = biasL[nt * 16 + lm];

    const float SC = 0.015625f;   // 1/64
    const int gy = y0 + wvid;
#pragma unroll
    for (int m = 0; m < 2; ++m) {
#pragma unroll
        for (int r = 0; r < 4; ++r) {
            float v0 = acc[m][0][r] * SC + bsr[0];
            float v1 = acc[m][1][r] * SC + bsr[1];
            float v2 = acc[m][2][r] * SC + bsr[2];
            float v3 = acc[m][3][r] * SC + bsr[3];

            float g0 = rowmax16(v0);
            float g1 = rowmax16(v1);
            float g2 = rowmax16(v2);
            float g3 = rowmax16(v3);
            int bg = 0; float best = g0;
            if (g1 > best) { best = g1; bg = 1; }
            if (g2 > best) { best = g2; bg = 2; }
            if (g3 > best) { best = g3; bg = 3; }

            float selv = (bg == 0) ? v0 : (bg == 1) ? v1 : (bg == 2) ? v2 : v3;

            const int gx = x0 + m * 16 + q * 4 + r;
            const size_t opix = ((size_t)bz * H + gy) * W + gx;
            out_sel[opix * 16 + lm] = selv;

            if (lm == 0) {
                out_idx[opix] = (float)bg;
                float o1v = (bg == 0) ? g1 : g0;
                float o2v = (bg <= 1) ? g2 : g1;
                float o3v = (bg <= 2) ? g3 : g2;
                float second = fmaxf(o1v, fmaxf(o2v, o3v));
                if (best - second < GAP_TAU) {
                    unsigned slot = atomicAdd(fix_cnt, 1u);
                    if (slot < FIX_CAP) fix_list[slot] = (unsigned)opix;
                }
            }
        }
    }
}

// fp64 exact recompute of flagged pixels; one wave per pixel, lane = oc
__global__ void fixup_kernel(const float* __restrict__ x, const int* __restrict__ gidx,
                             const float* __restrict__ w, const float* __restrict__ bias,
                             float* __restrict__ out_sel, float* __restrict__ out_idx,
                             const unsigned* __restrict__ fix_cnt,
                             const unsigned* __restrict__ fix_list)
{
    unsigned n = *fix_cnt;
    if (n > FIX_CAP) n = FIX_CAP;
    const int lane = threadIdx.x & 63;
    const int nwaves = gridDim.x * (blockDim.x >> 6);
    unsigned widx = blockIdx.x * (blockDim.x >> 6) + (threadIdx.x >> 6);

    for (; widx < n; widx += nwaves) {
        unsigned opix = fix_list[widx];
        int b  = opix >> 16;
        int y  = (opix >> 8) & 255;
        int xc = opix & 255;
        double acc = (double)bias[lane];
        for (int dy = 0; dy < 3; ++dy) {
            int yy = y + dy - 1;
            if (yy < 0 || yy >= H) continue;
            for (int dx = 0; dx < 3; ++dx) {
                int xx = xc + dx - 1;
                if (xx < 0 || xx >= W) continue;
                size_t pix = ((size_t)b * H + yy) * W + xx;
                int g = gidx[pix];
                const float* xp = x + pix * 16;
                const float* wp = w + (size_t)(lane * 64 + g * 16) * 9 + (dy * 3 + dx);
#pragma unroll
                for (int c = 0; c < 16; ++c)
                    acc = fma((double)wp[c * 9], (double)xp[c], acc);
            }
        }
        double m = acc;
        m = fmax(m, __shfl_xor(m, 1, 64));
        m = fmax(m, __shfl_xor(m, 2, 64));
        m = fmax(m, __shfl_xor(m, 4, 64));
        m = fmax(m, __shfl_xor(m, 8, 64));
        double g0 = __shfl(m, 0, 64), g1 = __shfl(m, 16, 64);
        double g2 = __shfl(m, 32, 64), g3 = __shfl(m, 48, 64);
        int bg = 0; double bb = g0;
        if (g1 > bb) { bb = g1; bg = 1; }
        if (g2 > bb) { bb = g2; bg = 2; }
        if (g3 > bb) { bb = g3; bg = 3; }
        if ((lane >> 4) == bg) out_sel[(size_t)opix * 16 + (lane & 15)] = (float)acc;
        if (lane == 0) out_idx[opix] = (float)bg;
    }
}

extern "C" void kernel_launch(void* const* d_in, const int* in_sizes, int n_in,
                              void* d_out, int out_size, void* d_ws, size_t ws_size,
                              hipStream_t stream) {
    const float* x    = (const float*)d_in[0];
    const int*   gidx = (const int*)d_in[1];
    const float* w    = (const float*)d_in[2];
    const float* bias = (const float*)d_in[3];

    unsigned short* wt = (unsigned short*)d_ws;                    // 73728 B
    unsigned* fix_cnt  = (unsigned*)((char*)d_ws + 73728);         // 16 B
    unsigned* fix_list = (unsigned*)((char*)d_ws + 73744);         // 64 KB

    float* out_sel = (float*)d_out;                               // 8*256*256*16
    float* out_idx = (float*)d_out + (size_t)BATCH * H * W * CIN; // 8*256*256

    wprep_kernel<<<64, 64, 0, stream>>>(w, wt, fix_cnt);

    dim3 grid(W / TW, H / TH, BATCH);   // 8 x 64 x 8 = 4096 blocks
    ssconv_f16_kernel<<<grid, 256, 0, stream>>>(x, gidx, wt, bias,
                                                out_sel, out_idx, fix_cnt, fix_list);
    fixup_kernel<<<256, 256, 0, stream>>>(x, gidx, w, bias, out_sel, out_idx,
                                          fix_cnt, fix_list);
}